// Round 4
// baseline (458.439 us; speedup 1.0000x reference)
//
#include <hip/hip_runtime.h>
#include <math.h>

typedef __attribute__((ext_vector_type(8))) short short8;
typedef __attribute__((ext_vector_type(4))) float f32x4;

#define B 8
#define H 128
#define W 128
#define UPC 64
#define CIN 66
#define BN_EPS 1e-5f

// ---- ws layout ----
// u16:   [0, 8388608)   up (bf16)  plane = 16384 u16 per (b,oc)
// u16:   [BSQ_U16, +BSQ_CNT) squeeze-B fragment stream
// u16:   [BF_U16, +BF_CNT)   fused-B fragment stream
// float: [SC_F, +594) scale, [SH_F, +594) shift
#define BSQ_U16  ((size_t)16777216)
#define BSQ_CNT  32768                /* 8 kc * 8 nt * 64 * 8 */
#define BF_U16   (BSQ_U16 + BSQ_CNT)
#define BF_CNT   38912                /* 19 ks * 4 nt * 64 * 8 */
#define SC_F     ((size_t)8424448)
#define SH_F     (SC_F + 594)

// precise RNE (prep only)
static __device__ __forceinline__ unsigned short f2bf(float f) {
    unsigned u = __float_as_uint(f);
    u += 0x7fffu + ((u >> 16) & 1u);
    return (unsigned short)(u >> 16);
}
// fast pack: round-half-up + v_perm_b32
static __device__ __forceinline__ unsigned pack2(float lo, float hi) {
    return __builtin_amdgcn_perm(__float_as_uint(hi) + 0x8000u,
                                 __float_as_uint(lo) + 0x8000u, 0x07060302u);
}

// ------------------------------------------------------------------
// prep: BN fold + B-operand fragment streams
// ------------------------------------------------------------------
__global__ void prep_kernel(const float* __restrict__ w_squeeze,
                            const float* __restrict__ gamma,
                            const float* __restrict__ beta,
                            const float* __restrict__ mean,
                            const float* __restrict__ var,
                            const float* __restrict__ w_conv,
                            float* __restrict__ ws)
{
    unsigned short* wsu = (unsigned short*)ws;
    int tid = blockIdx.x * blockDim.x + threadIdx.x;
    int nth = gridDim.x * blockDim.x;

    for (int idx = tid; idx < BSQ_CNT; idx += nth) {
        int j = idx & 7, lane = (idx >> 3) & 63, r = idx >> 9;
        int nt = r & 7, kc = r >> 3;
        int k = kc * 32 + ((lane >> 4) << 3) + j;
        int n = nt * 16 + (lane & 15);
        wsu[BSQ_U16 + idx] = f2bf(w_squeeze[n * 256 + k]);
    }
    for (int idx = tid; idx < BF_CNT; idx += nth) {
        int j = idx & 7, lane = (idx >> 3) & 63, r = idx >> 9;
        int nt = r & 3, ks = r >> 2;
        int k = ks * 32 + ((lane >> 4) << 3) + j;
        int n = nt * 16 + (lane & 15);
        float v = (k < 594) ? w_conv[n * 594 + k] : 0.f;
        wsu[BF_U16 + idx] = f2bf(v);
    }
    for (int i = tid; i < CIN * 9; i += nth) {
        float sc = gamma[i] / sqrtf(var[i] + BN_EPS);
        ws[SC_F + i] = sc;
        ws[SH_F + i] = beta[i] - mean[i] * sc;
    }
}

// ------------------------------------------------------------------
// squeeze: space-to-depth + 1x1 conv as bf16 MFMA GEMM
//   thread t: oct = t>>5 (channel octet), pp = t&31 (pixel pair)
//   16 float4 loads all in flight; up written as bf16
// ------------------------------------------------------------------
__global__ __launch_bounds__(256, 4) void squeeze_mfma(
    const float* __restrict__ x,
    float* __restrict__ wsp,
    float* __restrict__ out)
{
    __shared__ uint4 As[32 * 64];   // 32768 B

    const int m0 = blockIdx.x * 64;
    const int w0 = m0 & 127;
    const int h  = (m0 >> 7) & 127;
    const int b  = m0 >> 14;
    const int tid  = threadIdx.x;
    const int lane = tid & 63;
    const int wv   = tid >> 6;
    const int oct = tid >> 5;       // 0..7
    const int pp  = tid & 31;       // pixel pair

    // ---- A loads: 16 float4, all issued up front ----
    float4 v[2][8];
#pragma unroll
    for (int gy = 0; gy < 2; ++gy)
#pragma unroll
        for (int i = 0; i < 8; ++i)
            v[gy][i] = *(const float4*)(x +
                (size_t)(b * 64 + oct * 8 + i) * 65536 +
                (2 * h + gy) * 256 + 2 * w0 + 4 * pp);

    // ---- pack to fragment rows: row r=(gy+2*gx)*8+oct, pixel 2pp+p ----
#pragma unroll
    for (int gy = 0; gy < 2; ++gy)
#pragma unroll
        for (int gx = 0; gx < 2; ++gx)
#pragma unroll
            for (int p = 0; p < 2; ++p) {
                const int comp = p * 2 + gx;
                uint4 u;
                u.x = pack2(((const float*)&v[gy][0])[comp], ((const float*)&v[gy][1])[comp]);
                u.y = pack2(((const float*)&v[gy][2])[comp], ((const float*)&v[gy][3])[comp]);
                u.z = pack2(((const float*)&v[gy][4])[comp], ((const float*)&v[gy][5])[comp]);
                u.w = pack2(((const float*)&v[gy][6])[comp], ((const float*)&v[gy][7])[comp]);
                As[((gy + 2 * gx) * 8 + oct) * 64 + 2 * pp + p] = u;
            }

    // ---- B preload (latency drains under the barrier) ----
    const unsigned short* bsq = (const unsigned short*)wsp + BSQ_U16;
    short8 breg[2][8];
#pragma unroll
    for (int ks = 0; ks < 8; ++ks)
#pragma unroll
        for (int j = 0; j < 2; ++j)
            breg[j][ks] = *(const short8*)(bsq +
                (size_t)((ks * 8 + (2 * wv + j)) * 64 + lane) * 8);

    __syncthreads();

    // ---- MFMA: 4 mt x 2 nt per wave ----
    const int q = lane >> 4, m = lane & 15;
    f32x4 acc[4][2];
#pragma unroll
    for (int mt = 0; mt < 4; ++mt)
#pragma unroll
        for (int j = 0; j < 2; ++j) acc[mt][j] = (f32x4){0.f, 0.f, 0.f, 0.f};

#pragma unroll
    for (int ks = 0; ks < 8; ++ks)
#pragma unroll
        for (int mt = 0; mt < 4; ++mt) {
            short8 a = *(const short8*)&As[(ks * 4 + q) * 64 + mt * 16 + m];
            acc[mt][0] = __builtin_amdgcn_mfma_f32_16x16x32_bf16(a, breg[0][ks], acc[mt][0], 0, 0, 0);
            acc[mt][1] = __builtin_amdgcn_mfma_f32_16x16x32_bf16(a, breg[1][ks], acc[mt][1], 0, 0, 0);
        }

    // ---- epilogue: waves 0,1 -> up (bf16); waves 2,3 -> out (fp32) ----
    if (wv < 2) {
        unsigned short* upw = (unsigned short*)wsp;
#pragma unroll
        for (int j = 0; j < 2; ++j) {
            const int oc = (2 * wv + j) * 16 + m;
#pragma unroll
            for (int mt = 0; mt < 4; ++mt) {
                uint2 st;
                st.x = pack2(acc[mt][j][0], acc[mt][j][1]);
                st.y = pack2(acc[mt][j][2], acc[mt][j][3]);
                *(uint2*)(upw + (size_t)(b * 64 + oc) * 16384 + h * 128
                          + (w0 + mt * 16 + q * 4)) = st;
            }
        }
    } else {
#pragma unroll
        for (int j = 0; j < 2; ++j) {
            const int oc = (2 * wv + j) * 16 + m;
            const int lc = oc - 64;
            const int ch = (lc & 1) ? (96 + ((lc - 1) >> 1)) : (32 + (lc >> 1));
#pragma unroll
            for (int mt = 0; mt < 4; ++mt) {
                float4 st = {acc[mt][j][0], acc[mt][j][1], acc[mt][j][2], acc[mt][j][3]};
                *(float4*)(out + ((size_t)(b * 128 + ch) * 128 + h) * 128
                           + (w0 + mt * 16 + q * 4)) = st;
            }
        }
    }
}

// ------------------------------------------------------------------
// fused helpers
// ------------------------------------------------------------------
__device__ __forceinline__ void fs_from_n(
    int cu, const float n[9],
    const float* __restrict__ w_gw, const float* __restrict__ w_gf,
    const float* __restrict__ scp, const float* __restrict__ shp,
    float fs[9])
{
    const float p = (n[0] + n[1] + n[2] + n[3] + n[4] + n[5] + n[6] + n[7] + n[8]) * (1.f / 9.f);
    const float* gw = w_gw + cu * 9;
    const float* gf = w_gf + cu * 81;
    const float* sc = scp + cu * 9;
    const float* sh = shp + cu * 9;
    float e[9], se = 0.f;
#pragma unroll
    for (int j = 0; j < 9; ++j) { e[j] = __expf(p * gw[j]); se += e[j]; }
    const float sinv = 1.f / se;
#pragma unroll
    for (int j = 0; j < 9; ++j) {
        float cv = n[0] * gf[j * 9 + 0];
        cv = fmaf(n[1], gf[j * 9 + 1], cv); cv = fmaf(n[2], gf[j * 9 + 2], cv);
        cv = fmaf(n[3], gf[j * 9 + 3], cv); cv = fmaf(n[4], gf[j * 9 + 4], cv);
        cv = fmaf(n[5], gf[j * 9 + 5], cv); cv = fmaf(n[6], gf[j * 9 + 6], cv);
        cv = fmaf(n[7], gf[j * 9 + 7], cv); cv = fmaf(n[8], gf[j * 9 + 8], cv);
        float f = fmaf(cv, sc[j], sh[j]);
        fs[j] = fmaxf(f, 0.f) * (e[j] * sinv);
    }
}

__device__ __forceinline__ void pack_into(unsigned* pk, int ci, const float fs[9], float& carry)
{
    const int off = 9 * ci;
    if ((ci & 1) == 0) {
#pragma unroll
        for (int t = 0; t < 4; ++t) pk[off / 2 + t] = pack2(fs[2 * t], fs[2 * t + 1]);
        carry = fs[8];
    } else {
        pk[(off - 1) / 2] = pack2(carry, fs[0]);
#pragma unroll
        for (int t = 0; t < 4; ++t) pk[(off + 1) / 2 + t] = pack2(fs[1 + 2 * t], fs[2 + 2 * t]);
    }
}

__device__ __forceinline__ void coord_n(int which, int h0, int w0, int lane, float n[9])
{
    const int px = lane & 7, py = lane >> 3;
#pragma unroll
    for (int dy = 0; dy < 3; ++dy)
#pragma unroll
        for (int dx = 0; dx < 3; ++dx) {
            const int gy = h0 + py - 1 + dy, gx = w0 + px - 1 + dx;
            const bool ok = ((unsigned)gy < 128u) & ((unsigned)gx < 128u);
            const float v = (which == 0) ? (gx * (2.f / 127.f) - 1.f)
                                         : (gy * (2.f / 127.f) - 1.f);
            n[dy * 3 + dx] = ok ? v : 0.f;
        }
}

template<int NSTEPS>
__device__ __forceinline__ void do_mfma(
    int base, const uint4* As, const unsigned short* __restrict__ bfw,
    int wv, int lane, f32x4 acc[2][2])
{
    const int q = lane >> 4, m = lane & 15;
    const int ntb = (wv >> 1) * 2;
    const int pt0 = (wv & 1) * 2;
#pragma unroll
    for (int ks = 0; ks < NSTEPS; ++ks) {
        short8 b0 = *(const short8*)(bfw + (size_t)(((base + ks) * 4 + ntb + 0) * 64 + lane) * 8);
        short8 b1 = *(const short8*)(bfw + (size_t)(((base + ks) * 4 + ntb + 1) * 64 + lane) * 8);
#pragma unroll
        for (int mt = 0; mt < 2; ++mt) {
            short8 a = *(const short8*)&As[(ks * 4 + q) * 64 + (pt0 + mt) * 16 + m];
            acc[mt][0] = __builtin_amdgcn_mfma_f32_16x16x32_bf16(a, b0, acc[mt][0], 0, 0, 0);
            acc[mt][1] = __builtin_amdgcn_mfma_f32_16x16x32_bf16(a, b1, acc[mt][1], 0, 0, 0);
        }
    }
}

// ------------------------------------------------------------------
// fused: per-wave LDS micro-tile (bf16 up), fs on VALU, matvec on MFMA
// ------------------------------------------------------------------
__global__ __launch_bounds__(256, 3) void fused_mfma(
    const float* __restrict__ wsp,
    const float* __restrict__ w_gw,
    const float* __restrict__ w_gf,
    const float* __restrict__ b_conv,
    float* __restrict__ out)
{
    __shared__ uint4          As[40 * 64];     // 40960 B
    __shared__ unsigned short tiles[4][160];   // 1280 B: per-wave 10x16 bf16

    const int bx = blockIdx.x;
    const int w0 = (bx & 15) * 8;
    const int h0 = ((bx >> 4) & 15) * 8;
    const int b  = bx >> 8;
    const int tid = threadIdx.x, lane = tid & 63, wv = tid >> 6;
    const int px = lane & 7, py = lane >> 3;
    const bool interior = (h0 > 0) & (h0 < 120) & (w0 > 0) & (w0 < 120);

    const unsigned short* upb = (const unsigned short*)wsp + (size_t)b * UPC * 16384;
    const float* scp = wsp + SC_F;
    const float* shp = wsp + SH_F;
    const unsigned short* bfw = (const unsigned short*)wsp + BF_U16;

    // tile loader mapping: 40 lanes, row lr=lane>>2 (0..9), seg=lane&3 (4 u16 each)
    const int lr = lane >> 2, seg = lane & 3;
    const bool loader = lr < 10;
    int gyr = h0 - 1 + lr; gyr = min(max(gyr, 0), 127);
    int c0w = w0 - 4 + seg * 4; c0w = min(max(c0w, 0), 124);
    const size_t gposo = (size_t)gyr * 128 + c0w;
    unsigned short* tw = &tiles[wv][0];
    const int tco = lr * 16 + seg * 4;

    f32x4 acc[2][2];
#pragma unroll
    for (int mt = 0; mt < 2; ++mt)
#pragma unroll
        for (int j = 0; j < 2; ++j) acc[mt][j] = (f32x4){0.f, 0.f, 0.f, 0.f};

#pragma unroll 1
    for (int chunk = 0; chunk < 2; ++chunk) {
        const int cbase = chunk * 32 + 8 * wv;
        unsigned pk[36];
        float carry = 0.f;
        uint2 ldc, ldn;
        if (loader) ldc = *(const uint2*)(upb + (size_t)cbase * 16384 + gposo);

#pragma unroll
        for (int ci = 0; ci < 8; ++ci) {
            if (loader) *(uint2*)(tw + tco) = ldc;               // publish current
            if (ci < 7 && loader)                                // prefetch next
                ldn = *(const uint2*)(upb + (size_t)(cbase + ci + 1) * 16384 + gposo);

            float n[9];
#pragma unroll
            for (int dy = 0; dy < 3; ++dy)
#pragma unroll
                for (int dx = 0; dx < 3; ++dx) {
                    unsigned uv = tw[(py + dy) * 16 + 3 + px + dx];
                    float f = __uint_as_float(uv << 16);
                    if (!interior) {
                        const int gy = h0 + py - 1 + dy, gx = w0 + px - 1 + dx;
                        const bool ok = ((unsigned)gy < 128u) & ((unsigned)gx < 128u);
                        f = ok ? f : 0.f;
                    }
                    n[dy * 3 + dx] = f;
                }

            const int cu = __builtin_amdgcn_readfirstlane(cbase + ci);
            float fs[9];
            fs_from_n(cu, n, w_gw, w_gf, scp, shp, fs);
            pack_into(pk, ci, fs, carry);
            ldc = ldn;
        }

        float fsA[9], fsB[9];
        if (chunk == 1 && wv == 3) {     // coordinate channels 64, 65 (exact fp32)
            float n2[9];
            coord_n(0, h0, w0, lane, n2);
            fs_from_n(64, n2, w_gw, w_gf, scp, shp, fsA);
            coord_n(1, h0, w0, lane, n2);
            fs_from_n(65, n2, w_gw, w_gf, scp, shp, fsB);
        }

        __syncthreads();   // previous chunk's MFMA done reading As
#pragma unroll
        for (int kb = 0; kb < 9; ++kb)
            As[(9 * wv + kb) * 64 + lane] =
                (uint4){pk[4 * kb], pk[4 * kb + 1], pk[4 * kb + 2], pk[4 * kb + 3]};
        if (chunk == 1 && wv == 3) {
            uint4 v;
            v.x = pack2(fsA[0], fsA[1]); v.y = pack2(fsA[2], fsA[3]);
            v.z = pack2(fsA[4], fsA[5]); v.w = pack2(fsA[6], fsA[7]);
            As[36 * 64 + lane] = v;
            v.x = pack2(fsA[8], fsB[0]); v.y = pack2(fsB[1], fsB[2]);
            v.z = pack2(fsB[3], fsB[4]); v.w = pack2(fsB[5], fsB[6]);
            As[37 * 64 + lane] = v;
            v.x = pack2(fsB[7], fsB[8]); v.y = 0u; v.z = 0u; v.w = 0u;
            As[38 * 64 + lane] = v;
            v.x = 0u; v.y = 0u; v.z = 0u; v.w = 0u;
            As[39 * 64 + lane] = v;
        }
        __syncthreads();

        if (chunk == 0) do_mfma<9>(0, As, bfw, wv, lane, acc);
        else            do_mfma<10>(9, As, bfw, wv, lane, acc);
    }

    // ---- epilogue ----
    const int q = lane >> 4, m = lane & 15;
    const int ntb = (wv >> 1) * 2, pt0 = (wv & 1) * 2;
#pragma unroll
    for (int mt = 0; mt < 2; ++mt)
#pragma unroll
        for (int j = 0; j < 2; ++j) {
            const int oc = (ntb + j) * 16 + m;
            const float bias = b_conv[oc];
            const int ch = (oc & 1) ? (64 + (oc >> 1)) : (oc >> 1);
#pragma unroll
            for (int r = 0; r < 4; ++r) {
                const int pix = (pt0 + mt) * 16 + q * 4 + r;
                out[((size_t)((b * 128 + ch) * 128 + (h0 + (pix >> 3)))) * 128
                    + (w0 + (pix & 7))] = acc[mt][j][r] + bias;
            }
        }
}

// ------------------------------------------------------------------
extern "C" void kernel_launch(void* const* d_in, const int* in_sizes, int n_in,
                              void* d_out, int out_size, void* d_ws, size_t ws_size,
                              hipStream_t stream)
{
    const float* x         = (const float*)d_in[0];
    const float* w_squeeze = (const float*)d_in[1];
    const float* w_gw      = (const float*)d_in[2];
    const float* w_gf      = (const float*)d_in[3];
    const float* gamma     = (const float*)d_in[4];
    const float* beta      = (const float*)d_in[5];
    const float* mean      = (const float*)d_in[6];
    const float* var       = (const float*)d_in[7];
    const float* w_conv    = (const float*)d_in[8];
    const float* b_conv    = (const float*)d_in[9];
    float* out = (float*)d_out;
    float* ws  = (float*)d_ws;

    prep_kernel<<<160, 256, 0, stream>>>(w_squeeze, gamma, beta, mean, var, w_conv, ws);
    squeeze_mfma<<<(B * H * W) / 64, 256, 0, stream>>>(x, ws, out);
    fused_mfma<<<B * 16 * 16, 256, 0, stream>>>(ws, w_gw, w_gf, b_conv, out);
}

// Round 5
// 324.786 us; speedup vs baseline: 1.4115x; 1.4115x over previous
//
#include <hip/hip_runtime.h>
#include <math.h>

typedef __attribute__((ext_vector_type(8))) short short8;
typedef __attribute__((ext_vector_type(4))) float f32x4;

#define B 8
#define H 128
#define W 128
#define UPC 64
#define CIN 66
#define BN_EPS 1e-5f

// ---- ws layout ----
// u16:   [0, 8388608)   up (bf16)  plane = 16384 u16 per (b,oc)
// u16:   [BSQ_U16, +BSQ_CNT) squeeze-B fragment stream
// u16:   [BF_U16, +BF_CNT)   fused-B fragment stream
// float: [SC_F, +594) scale, [SH_F, +594) shift
#define BSQ_U16  ((size_t)16777216)
#define BSQ_CNT  32768                /* 8 kc * 8 nt * 64 * 8 */
#define BF_U16   (BSQ_U16 + BSQ_CNT)
#define BF_CNT   38912                /* 19 ks * 4 nt * 64 * 8 */
#define SC_F     ((size_t)8424448)
#define SH_F     (SC_F + 594)

// precise RNE (prep only)
static __device__ __forceinline__ unsigned short f2bf(float f) {
    unsigned u = __float_as_uint(f);
    u += 0x7fffu + ((u >> 16) & 1u);
    return (unsigned short)(u >> 16);
}
// fast pack: round-half-up + v_perm_b32
static __device__ __forceinline__ unsigned pack2(float lo, float hi) {
    return __builtin_amdgcn_perm(__float_as_uint(hi) + 0x8000u,
                                 __float_as_uint(lo) + 0x8000u, 0x07060302u);
}

// ------------------------------------------------------------------
// prep: BN fold + B-operand fragment streams
// ------------------------------------------------------------------
__global__ void prep_kernel(const float* __restrict__ w_squeeze,
                            const float* __restrict__ gamma,
                            const float* __restrict__ beta,
                            const float* __restrict__ mean,
                            const float* __restrict__ var,
                            const float* __restrict__ w_conv,
                            float* __restrict__ ws)
{
    unsigned short* wsu = (unsigned short*)ws;
    int tid = blockIdx.x * blockDim.x + threadIdx.x;
    int nth = gridDim.x * blockDim.x;

    for (int idx = tid; idx < BSQ_CNT; idx += nth) {
        int j = idx & 7, lane = (idx >> 3) & 63, r = idx >> 9;
        int nt = r & 7, kc = r >> 3;
        int k = kc * 32 + ((lane >> 4) << 3) + j;
        int n = nt * 16 + (lane & 15);
        wsu[BSQ_U16 + idx] = f2bf(w_squeeze[n * 256 + k]);
    }
    for (int idx = tid; idx < BF_CNT; idx += nth) {
        int j = idx & 7, lane = (idx >> 3) & 63, r = idx >> 9;
        int nt = r & 3, ks = r >> 2;
        int k = ks * 32 + ((lane >> 4) << 3) + j;
        int n = nt * 16 + (lane & 15);
        float v = (k < 594) ? w_conv[n * 594 + k] : 0.f;
        wsu[BF_U16 + idx] = f2bf(v);
    }
    for (int i = tid; i < CIN * 9; i += nth) {
        float sc = gamma[i] / sqrtf(var[i] + BN_EPS);
        ws[SC_F + i] = sc;
        ws[SH_F + i] = beta[i] - mean[i] * sc;
    }
}

// ------------------------------------------------------------------
// squeeze: space-to-depth + 1x1 conv as bf16 MFMA GEMM  (R4 version, kept)
// ------------------------------------------------------------------
__global__ __launch_bounds__(256, 4) void squeeze_mfma(
    const float* __restrict__ x,
    float* __restrict__ wsp,
    float* __restrict__ out)
{
    __shared__ uint4 As[32 * 64];   // 32768 B

    const int m0 = blockIdx.x * 64;
    const int w0 = m0 & 127;
    const int h  = (m0 >> 7) & 127;
    const int b  = m0 >> 14;
    const int tid  = threadIdx.x;
    const int lane = tid & 63;
    const int wv   = tid >> 6;
    const int oct = tid >> 5;       // 0..7
    const int pp  = tid & 31;       // pixel pair

    // ---- A loads: 16 float4, all issued up front ----
    float4 v[2][8];
#pragma unroll
    for (int gy = 0; gy < 2; ++gy)
#pragma unroll
        for (int i = 0; i < 8; ++i)
            v[gy][i] = *(const float4*)(x +
                (size_t)(b * 64 + oct * 8 + i) * 65536 +
                (2 * h + gy) * 256 + 2 * w0 + 4 * pp);

    // ---- pack to fragment rows: row r=(gy+2*gx)*8+oct, pixel 2pp+p ----
#pragma unroll
    for (int gy = 0; gy < 2; ++gy)
#pragma unroll
        for (int gx = 0; gx < 2; ++gx)
#pragma unroll
            for (int p = 0; p < 2; ++p) {
                const int comp = p * 2 + gx;
                uint4 u;
                u.x = pack2(((const float*)&v[gy][0])[comp], ((const float*)&v[gy][1])[comp]);
                u.y = pack2(((const float*)&v[gy][2])[comp], ((const float*)&v[gy][3])[comp]);
                u.z = pack2(((const float*)&v[gy][4])[comp], ((const float*)&v[gy][5])[comp]);
                u.w = pack2(((const float*)&v[gy][6])[comp], ((const float*)&v[gy][7])[comp]);
                As[((gy + 2 * gx) * 8 + oct) * 64 + 2 * pp + p] = u;
            }

    // ---- B preload (latency drains under the barrier) ----
    const unsigned short* bsq = (const unsigned short*)wsp + BSQ_U16;
    short8 breg[2][8];
#pragma unroll
    for (int ks = 0; ks < 8; ++ks)
#pragma unroll
        for (int j = 0; j < 2; ++j)
            breg[j][ks] = *(const short8*)(bsq +
                (size_t)((ks * 8 + (2 * wv + j)) * 64 + lane) * 8);

    __syncthreads();

    // ---- MFMA: 4 mt x 2 nt per wave ----
    const int q = lane >> 4, m = lane & 15;
    f32x4 acc[4][2];
#pragma unroll
    for (int mt = 0; mt < 4; ++mt)
#pragma unroll
        for (int j = 0; j < 2; ++j) acc[mt][j] = (f32x4){0.f, 0.f, 0.f, 0.f};

#pragma unroll
    for (int ks = 0; ks < 8; ++ks)
#pragma unroll
        for (int mt = 0; mt < 4; ++mt) {
            short8 a = *(const short8*)&As[(ks * 4 + q) * 64 + mt * 16 + m];
            acc[mt][0] = __builtin_amdgcn_mfma_f32_16x16x32_bf16(a, breg[0][ks], acc[mt][0], 0, 0, 0);
            acc[mt][1] = __builtin_amdgcn_mfma_f32_16x16x32_bf16(a, breg[1][ks], acc[mt][1], 0, 0, 0);
        }

    // ---- epilogue: waves 0,1 -> up (bf16); waves 2,3 -> out (fp32) ----
    if (wv < 2) {
        unsigned short* upw = (unsigned short*)wsp;
#pragma unroll
        for (int j = 0; j < 2; ++j) {
            const int oc = (2 * wv + j) * 16 + m;
#pragma unroll
            for (int mt = 0; mt < 4; ++mt) {
                uint2 st;
                st.x = pack2(acc[mt][j][0], acc[mt][j][1]);
                st.y = pack2(acc[mt][j][2], acc[mt][j][3]);
                *(uint2*)(upw + (size_t)(b * 64 + oc) * 16384 + h * 128
                          + (w0 + mt * 16 + q * 4)) = st;
            }
        }
    } else {
#pragma unroll
        for (int j = 0; j < 2; ++j) {
            const int oc = (2 * wv + j) * 16 + m;
            const int lc = oc - 64;
            const int ch = (lc & 1) ? (96 + ((lc - 1) >> 1)) : (32 + (lc >> 1));
#pragma unroll
            for (int mt = 0; mt < 4; ++mt) {
                float4 st = {acc[mt][j][0], acc[mt][j][1], acc[mt][j][2], acc[mt][j][3]};
                *(float4*)(out + ((size_t)(b * 128 + ch) * 128 + h) * 128
                           + (w0 + mt * 16 + q * 4)) = st;
            }
        }
    }
}

// ------------------------------------------------------------------
// fused helpers (R3 structure)
// ------------------------------------------------------------------
__device__ __forceinline__ void fs_from_n(
    int cu, const float n[9],
    const float* __restrict__ w_gw, const float* __restrict__ w_gf,
    const float* __restrict__ scp, const float* __restrict__ shp,
    float fs[9])
{
    const float p = (n[0] + n[1] + n[2] + n[3] + n[4] + n[5] + n[6] + n[7] + n[8]) * (1.f / 9.f);
    const float* gw = w_gw + cu * 9;
    const float* gf = w_gf + cu * 81;
    const float* sc = scp + cu * 9;
    const float* sh = shp + cu * 9;
    float e[9], se = 0.f;
#pragma unroll
    for (int j = 0; j < 9; ++j) { e[j] = __expf(p * gw[j]); se += e[j]; }
    const float sinv = 1.f / se;
#pragma unroll
    for (int j = 0; j < 9; ++j) {
        float cv = n[0] * gf[j * 9 + 0];
        cv = fmaf(n[1], gf[j * 9 + 1], cv); cv = fmaf(n[2], gf[j * 9 + 2], cv);
        cv = fmaf(n[3], gf[j * 9 + 3], cv); cv = fmaf(n[4], gf[j * 9 + 4], cv);
        cv = fmaf(n[5], gf[j * 9 + 5], cv); cv = fmaf(n[6], gf[j * 9 + 6], cv);
        cv = fmaf(n[7], gf[j * 9 + 7], cv); cv = fmaf(n[8], gf[j * 9 + 8], cv);
        float f = fmaf(cv, sc[j], sh[j]);
        fs[j] = fmaxf(f, 0.f) * (e[j] * sinv);
    }
}

__device__ __forceinline__ void pack_into(unsigned* pk, int ci, const float fs[9], float& carry)
{
    const int off = 9 * ci;
    if ((ci & 1) == 0) {
#pragma unroll
        for (int t = 0; t < 4; ++t) pk[off / 2 + t] = pack2(fs[2 * t], fs[2 * t + 1]);
        carry = fs[8];
    } else {
        pk[(off - 1) / 2] = pack2(carry, fs[0]);
#pragma unroll
        for (int t = 0; t < 4; ++t) pk[(off + 1) / 2 + t] = pack2(fs[1 + 2 * t], fs[2 + 2 * t]);
    }
}

// interior: 3 aligned uint2 row loads per channel (cover cols c-1..c+1)
// border: clamped scalar loads + predicate zero
template<bool BORDER>
__device__ __forceinline__ void chunk_fs(
    int cs, int wv, int lane, int h0, int w0,
    const unsigned short* __restrict__ upb,
    const float* __restrict__ w_gw, const float* __restrict__ w_gf,
    const float* __restrict__ scp, const float* __restrict__ shp,
    unsigned pk[36])
{
    const int px = lane & 7, py = lane >> 3;
    const int gy0 = h0 + py - 1;
    const int gxc = w0 + px;
    float carry = 0.f;

    if (!BORDER) {
        const int gx0 = (gxc - 1) & ~1;             // aligned base col
        const unsigned sh = (gxc & 1) ? 0u : 16u;   // odd: cols at 0..2, even: 1..3
        const size_t rowoff = (size_t)gy0 * 128 + gx0;
#pragma unroll
        for (int ci = 0; ci < 8; ++ci) {
            const int cu = __builtin_amdgcn_readfirstlane(cs + 8 * wv + ci);
            const unsigned short* cb = upb + (size_t)cu * 16384 + rowoff;
            float n[9];
#pragma unroll
            for (int dy = 0; dy < 3; ++dy) {
                const uint2 v = *(const uint2*)(cb + dy * 128);
                unsigned long long t = (((unsigned long long)v.y) << 32) | v.x;
                t >>= sh;
                n[dy * 3 + 0] = __uint_as_float((unsigned)t << 16);
                n[dy * 3 + 1] = __uint_as_float((unsigned)t & 0xffff0000u);
                n[dy * 3 + 2] = __uint_as_float((unsigned)(t >> 32) << 16);
            }
            float fs[9];
            fs_from_n(cu, n, w_gw, w_gf, scp, shp, fs);
            pack_into(pk, ci, fs, carry);
        }
    } else {
#pragma unroll
        for (int ci = 0; ci < 8; ++ci) {
            const int cu = __builtin_amdgcn_readfirstlane(cs + 8 * wv + ci);
            const unsigned short* cb = upb + (size_t)cu * 16384;
            float n[9];
#pragma unroll
            for (int dy = 0; dy < 3; ++dy)
#pragma unroll
                for (int dx = 0; dx < 3; ++dx) {
                    const int gy = gy0 + dy, gx = gxc - 1 + dx;
                    const bool ok = ((unsigned)gy < 128u) & ((unsigned)gx < 128u);
                    const int cy = min(max(gy, 0), 127), cx = min(max(gx, 0), 127);
                    const float f = __uint_as_float((unsigned)cb[cy * 128 + cx] << 16);
                    n[dy * 3 + dx] = ok ? f : 0.f;
                }
            float fs[9];
            fs_from_n(cu, n, w_gw, w_gf, scp, shp, fs);
            pack_into(pk, ci, fs, carry);
        }
    }
}

__device__ __forceinline__ void coord_n(int which, int h0, int w0, int lane, float n[9])
{
    const int px = lane & 7, py = lane >> 3;
#pragma unroll
    for (int dy = 0; dy < 3; ++dy)
#pragma unroll
        for (int dx = 0; dx < 3; ++dx) {
            const int gy = h0 + py - 1 + dy, gx = w0 + px - 1 + dx;
            const bool ok = ((unsigned)gy < 128u) & ((unsigned)gx < 128u);
            const float v = (which == 0) ? (gx * (2.f / 127.f) - 1.f)
                                         : (gy * (2.f / 127.f) - 1.f);
            n[dy * 3 + dx] = ok ? v : 0.f;
        }
}

template<int NSTEPS>
__device__ __forceinline__ void do_mfma(
    int base, const uint4* As, const unsigned short* __restrict__ bfw,
    int wv, int lane, f32x4 acc[2][2])
{
    const int q = lane >> 4, m = lane & 15;
    const int ntb = (wv >> 1) * 2;
    const int pt0 = (wv & 1) * 2;
#pragma unroll
    for (int ks = 0; ks < NSTEPS; ++ks) {
        short8 b0 = *(const short8*)(bfw + (size_t)(((base + ks) * 4 + ntb + 0) * 64 + lane) * 8);
        short8 b1 = *(const short8*)(bfw + (size_t)(((base + ks) * 4 + ntb + 1) * 64 + lane) * 8);
#pragma unroll
        for (int mt = 0; mt < 2; ++mt) {
            short8 a = *(const short8*)&As[(ks * 4 + q) * 64 + (pt0 + mt) * 16 + m];
            acc[mt][0] = __builtin_amdgcn_mfma_f32_16x16x32_bf16(a, b0, acc[mt][0], 0, 0, 0);
            acc[mt][1] = __builtin_amdgcn_mfma_f32_16x16x32_bf16(a, b1, acc[mt][1], 0, 0, 0);
        }
    }
}

// ------------------------------------------------------------------
// fused: R3 structure, bf16 up, 3-row-load neighborhoods
// ------------------------------------------------------------------
__global__ __launch_bounds__(256, 4) void fused_mfma(
    const float* __restrict__ wsp,
    const float* __restrict__ w_gw,
    const float* __restrict__ w_gf,
    const float* __restrict__ b_conv,
    float* __restrict__ out)
{
    __shared__ uint4 As[40 * 64];   // 40960 B

    const int bx = blockIdx.x;
    const int w0 = (bx & 15) * 8;
    const int h0 = ((bx >> 4) & 15) * 8;
    const int b  = bx >> 8;
    const int tid = threadIdx.x, lane = tid & 63, wv = tid >> 6;
    const bool interior = (h0 > 0) & (h0 < 120) & (w0 > 0) & (w0 < 120);

    const unsigned short* upb = (const unsigned short*)wsp + (size_t)b * UPC * 16384;
    const float* scp = wsp + SC_F;
    const float* shp = wsp + SH_F;
    const unsigned short* bfw = (const unsigned short*)wsp + BF_U16;

    f32x4 acc[2][2];
#pragma unroll
    for (int mt = 0; mt < 2; ++mt)
#pragma unroll
        for (int j = 0; j < 2; ++j) acc[mt][j] = (f32x4){0.f, 0.f, 0.f, 0.f};

    // ================= chunk 0 : channels 0..31 =================
    {
        unsigned pk[36];
        if (interior) chunk_fs<false>(0, wv, lane, h0, w0, upb, w_gw, w_gf, scp, shp, pk);
        else          chunk_fs<true >(0, wv, lane, h0, w0, upb, w_gw, w_gf, scp, shp, pk);
        __syncthreads();
#pragma unroll
        for (int kb = 0; kb < 9; ++kb)
            As[(9 * wv + kb) * 64 + lane] =
                (uint4){pk[4 * kb], pk[4 * kb + 1], pk[4 * kb + 2], pk[4 * kb + 3]};
        __syncthreads();
        do_mfma<9>(0, As, bfw, wv, lane, acc);
    }

    // ================= chunk 1 : channels 32..65 + pad =================
    {
        unsigned pk[36];
        if (interior) chunk_fs<false>(32, wv, lane, h0, w0, upb, w_gw, w_gf, scp, shp, pk);
        else          chunk_fs<true >(32, wv, lane, h0, w0, upb, w_gw, w_gf, scp, shp, pk);

        float fsA[9], fsB[9];
        if (wv == 3) {   // coordinate channels 64, 65 (exact fp32)
            float n2[9];
            coord_n(0, h0, w0, lane, n2);
            fs_from_n(64, n2, w_gw, w_gf, scp, shp, fsA);
            coord_n(1, h0, w0, lane, n2);
            fs_from_n(65, n2, w_gw, w_gf, scp, shp, fsB);
        }
        __syncthreads();   // chunk0 MFMA done reading As
#pragma unroll
        for (int kb = 0; kb < 9; ++kb)
            As[(9 * wv + kb) * 64 + lane] =
                (uint4){pk[4 * kb], pk[4 * kb + 1], pk[4 * kb + 2], pk[4 * kb + 3]};
        if (wv == 3) {
            uint4 v;
            v.x = pack2(fsA[0], fsA[1]); v.y = pack2(fsA[2], fsA[3]);
            v.z = pack2(fsA[4], fsA[5]); v.w = pack2(fsA[6], fsA[7]);
            As[36 * 64 + lane] = v;
            v.x = pack2(fsA[8], fsB[0]); v.y = pack2(fsB[1], fsB[2]);
            v.z = pack2(fsB[3], fsB[4]); v.w = pack2(fsB[5], fsB[6]);
            As[37 * 64 + lane] = v;
            v.x = pack2(fsB[7], fsB[8]); v.y = 0u; v.z = 0u; v.w = 0u;
            As[38 * 64 + lane] = v;
            v.x = 0u; v.y = 0u; v.z = 0u; v.w = 0u;
            As[39 * 64 + lane] = v;
        }
        __syncthreads();
        do_mfma<10>(9, As, bfw, wv, lane, acc);
    }

    // ================= epilogue =================
    const int q = lane >> 4, m = lane & 15;
    const int ntb = (wv >> 1) * 2, pt0 = (wv & 1) * 2;
#pragma unroll
    for (int mt = 0; mt < 2; ++mt)
#pragma unroll
        for (int j = 0; j < 2; ++j) {
            const int oc = (ntb + j) * 16 + m;
            const float bias = b_conv[oc];
            const int ch = (oc & 1) ? (64 + (oc >> 1)) : (oc >> 1);
#pragma unroll
            for (int r = 0; r < 4; ++r) {
                const int pix = (pt0 + mt) * 16 + q * 4 + r;
                out[((size_t)((b * 128 + ch) * 128 + (h0 + (pix >> 3)))) * 128
                    + (w0 + (pix & 7))] = acc[mt][j][r] + bias;
            }
        }
}

// ------------------------------------------------------------------
extern "C" void kernel_launch(void* const* d_in, const int* in_sizes, int n_in,
                              void* d_out, int out_size, void* d_ws, size_t ws_size,
                              hipStream_t stream)
{
    const float* x         = (const float*)d_in[0];
    const float* w_squeeze = (const float*)d_in[1];
    const float* w_gw      = (const float*)d_in[2];
    const float* w_gf      = (const float*)d_in[3];
    const float* gamma     = (const float*)d_in[4];
    const float* beta      = (const float*)d_in[5];
    const float* mean      = (const float*)d_in[6];
    const float* var       = (const float*)d_in[7];
    const float* w_conv    = (const float*)d_in[8];
    const float* b_conv    = (const float*)d_in[9];
    float* out = (float*)d_out;
    float* ws  = (float*)d_ws;

    prep_kernel<<<160, 256, 0, stream>>>(w_squeeze, gamma, beta, mean, var, w_conv, ws);
    squeeze_mfma<<<(B * H * W) / 64, 256, 0, stream>>>(x, ws, out);
    fused_mfma<<<B * 16 * 16, 256, 0, stream>>>(ws, w_gw, w_gf, b_conv, out);
}